// Round 13
// baseline (209.433 us; speedup 1.0000x reference)
//
#include <hip/hip_runtime.h>
#include <hip/hip_bf16.h>
#include <math.h>

// Problem constants
#define BROWS 16384
#define IN_DIM 128
#define HID 512
#define ATT 256
#define KTOT 896          // IN_DIM + HID + ATT
#define KC_TOT 112        // KTOT / 8

typedef __bf16 bf16x8 __attribute__((ext_vector_type(8)));
typedef float f32x4 __attribute__((ext_vector_type(4)));

// ---------------------------------------------------------------------------
// Kernel 1: pack augmented weights -> B_stage[jt(8)][kc(112)][nl(192)][8] bf16.
// nl = jg*48 + type*16 + j16 ; jg in [0,4), type 0=gate 1=dyn 2=tau.
// j = jt*64 + jg*16 + j16. tau rows ZERO outside k in [128,640).   (UNCHANGED)
// ---------------------------------------------------------------------------
__device__ __forceinline__ float softplus_f(float x) {
    return fmaxf(x, 0.0f) + log1pf(__expf(-fabsf(x)));
}

__global__ void pack_B(const float* __restrict__ W_gd, const float* __restrict__ W_tau,
                       const float* __restrict__ gleak, const float* __restrict__ cm,
                       __hip_bfloat16* __restrict__ B_stage, float* __restrict__ dconst) {
    const int cid = blockIdx.x * 256 + threadIdx.x;   // 672*256 = 172032 = 8*112*192
    if (cid < HID) {
        dconst[cid] = softplus_f(cm[cid]) + softplus_f(gleak[cid]) + 1e-6f;
    }
    const int nl = cid % 192;
    const int kc = (cid / 192) % KC_TOT;
    const int jt = cid / (192 * KC_TOT);
    const int jg = nl / 48, type = (nl % 48) / 16, j16 = nl % 16;
    const int j = jt * 64 + jg * 16 + j16;
    const int k0 = kc * 8;

    float v[8];
    if (type == 0) {
        const float* s = W_gd + (size_t)j * KTOT + k0;
        #pragma unroll
        for (int i = 0; i < 8; ++i) v[i] = s[i];
    } else if (type == 1) {
        const float* s = W_gd + (size_t)(HID + j) * KTOT + k0;
        #pragma unroll
        for (int i = 0; i < 8; ++i) v[i] = s[i];
    } else {
        if (k0 >= IN_DIM && k0 < IN_DIM + HID) {
            const float* s = W_tau + (size_t)j * HID + (k0 - IN_DIM);
            #pragma unroll
            for (int i = 0; i < 8; ++i) v[i] = s[i];
        } else {
            #pragma unroll
            for (int i = 0; i < 8; ++i) v[i] = 0.0f;
        }
    }
    union { __hip_bfloat16 hh[8]; uint4 u; } p;
    #pragma unroll
    for (int i = 0; i < 8; ++i) p.hh[i] = __float2bfloat16(v[i]);
    *(uint4*)(B_stage + (size_t)cid * 8) = p.u;
}

// ---------------------------------------------------------------------------
// Kernel 2 — R13: WINDOWED A-staging (32KB LDS) to unlock 4 waves/SIMD.
// Serial-sum model of the R0-R12 invariant (64-72us): MFMA 18.6 + A-LDS-read
// 18 + B-L2 7 + ingest 8 + epilogue 9 ~= 61us with ZERO overlap, because
// every config so far had <=2 waves/SIMD (acc>=96 collides with the VGPR
// pool law cap=131072/threads; full-K A-tile 56-112KB collides with LDS).
// Exit: shrink LDS, not registers. A staged in K=128 windows (16KB x 2buf =
// 32KB), acc 48 (wave = 64r x 16j), simple loads (no rings) ~= 110 regs.
// (512,2) => 128-reg cap AND 2 blocks/CU resident = 16 waves/CU = 4/SIMD —
// first config in-session with both TLP and registers. B from L2 registers;
// 4-wave rotation hides its ~250cyc latency (the thesis under test).
// Windows map 1:1 to sources: w0=x, w1-4=h, w5-6=ctx. One barrier/window.
// Grid 1024 = 256 rowtiles x 4 j-quarters, XCD-chunk swizzle co-locates the
// 4 siblings sharing a rowtile (A re-reads hit their XCD's L2).
// Predict: Occupancy 19->35-45% (KEY tell), dur 35-48us, MfmaUtil 32-45%,
// VGPR 110-125, WRITE ~32.7MB clean, LDS 32768, conflicts ~0.
// ---------------------------------------------------------------------------
__global__ __launch_bounds__(512, 2) void ltc_gemm(
    const float* __restrict__ x, const float* __restrict__ h_ltc,
    const float* __restrict__ ctx, const __hip_bfloat16* __restrict__ B_stage,
    const float* __restrict__ b_gd, const float* __restrict__ b_tau,
    const float* __restrict__ dconst, float* __restrict__ out) {

    __shared__ __attribute__((aligned(16))) char As[2][16384];  // [kcl 16][row 64][16B]

    // XCD-chunk swizzle: 1024 wgs = 8 xcds x (32 rowtiles x 4 j-quarters)
    const int wgid = blockIdx.x;
    const int xcd = wgid & 7;
    const int idx = wgid >> 3;               // 0..127
    const int rt  = xcd * 32 + (idx >> 2);   // rowtile 0..255 (64 rows)
    const int jq  = idx & 3;                 // j-quarter (128 j)

    const int tid = threadIdx.x;
    const int wave = tid >> 6, lane = tid & 63;
    const int q = lane >> 4, t = lane & 15;

    // stager role: each thread loads 16 consecutive fp32 (2 kc-chunks) per window
    const int srow = tid >> 3;               // 0..63
    const int skc  = (tid & 7) * 2;          // 0,2,..,14

    float4 av[4];

    #define LOADW(w_) do {                                                        \
        const float* _src; int _rs, _c0;                                          \
        if ((w_) == 0)      { _src = x;     _rs = IN_DIM; _c0 = 0; }              \
        else if ((w_) < 5)  { _src = h_ltc; _rs = HID;    _c0 = ((w_)-1)*128; }   \
        else                { _src = ctx;   _rs = ATT;    _c0 = ((w_)-5)*128; }   \
        const float* _p = _src + (size_t)(rt*64 + srow)*_rs + _c0 + skc*8;        \
        av[0] = ((const float4*)_p)[0]; av[1] = ((const float4*)_p)[1];           \
        av[2] = ((const float4*)_p)[2]; av[3] = ((const float4*)_p)[3];           \
    } while (0)

    #define WRITEW(buf_, w_) do {                                                 \
        _Pragma("unroll")                                                         \
        for (int _c = 0; _c < 2; ++_c) {                                          \
            const int _kcl = skc + _c;                                            \
            const int _sw = (((w_)*16) + _kcl) & 31;                              \
            union { __hip_bfloat16 hh[8]; uint4 u; } _pk;                         \
            const float4 _lo = av[_c*2], _hi = av[_c*2+1];                        \
            _pk.hh[0]=__float2bfloat16(_lo.x); _pk.hh[1]=__float2bfloat16(_lo.y); \
            _pk.hh[2]=__float2bfloat16(_lo.z); _pk.hh[3]=__float2bfloat16(_lo.w); \
            _pk.hh[4]=__float2bfloat16(_hi.x); _pk.hh[5]=__float2bfloat16(_hi.y); \
            _pk.hh[6]=__float2bfloat16(_hi.z); _pk.hh[7]=__float2bfloat16(_hi.w); \
            *(uint4*)(&As[buf_][ ((_kcl*64) + (srow ^ _sw)) << 4 ]) = _pk.u;      \
        }                                                                         \
    } while (0)

    // ---- j setup (fixed per block: wave owns 64 rows x 16 j) ----
    const int jglob = jq * 128 + wave * 16;
    const int jt = jglob >> 6;               // 0..7
    const int jg = (jglob >> 4) & 3;         // 0..3
    const __hip_bfloat16* bBase = B_stage
        + ((size_t)jt * (KC_TOT * 192) + jg * 48 + t) * 8;

    f32x4 acc[4][3];
    #pragma unroll
    for (int rf = 0; rf < 4; ++rf)
        #pragma unroll
        for (int ty = 0; ty < 3; ++ty) acc[rf][ty] = (f32x4)0.0f;

    // ---- prologue: stage window 0 ----
    LOADW(0);
    WRITEW(0, 0);
    __syncthreads();

    // ---- K-loop: 7 windows x 4 K32-steps ----
    for (int w = 0; w < 7; ++w) {
        const int cb = w & 1;
        if (w < 6) LOADW(w + 1);             // issue next-window HBM loads early
        const bool tau_cur = (w >= 1 && w <= 4);   // k in [128,640)
        const char* Ab = As[cb];
        #pragma unroll
        for (int s = 0; s < 4; ++s) {
            const int kc  = w * 16 + s * 4 + q;    // global kc (B index + swizzle)
            const int kcl = s * 4 + q;             // local kc within window
            const int sw  = kc & 31;
            const bf16x8 a0 = *(const bf16x8*)(Ab + ((kcl*64 + ( t        ^ sw)) << 4));
            const bf16x8 a1 = *(const bf16x8*)(Ab + ((kcl*64 + ((16 + t)  ^ sw)) << 4));
            const bf16x8 a2 = *(const bf16x8*)(Ab + ((kcl*64 + ((32 + t)  ^ sw)) << 4));
            const bf16x8 a3 = *(const bf16x8*)(Ab + ((kcl*64 + ((48 + t)  ^ sw)) << 4));
            const __hip_bfloat16* bp = bBase + (size_t)kc * 1536;
            const bf16x8 bg = *(const bf16x8*)(bp);
            const bf16x8 bd = *(const bf16x8*)(bp + 128);
            acc[0][0] = __builtin_amdgcn_mfma_f32_16x16x32_bf16(a0, bg, acc[0][0], 0, 0, 0);
            acc[1][0] = __builtin_amdgcn_mfma_f32_16x16x32_bf16(a1, bg, acc[1][0], 0, 0, 0);
            acc[2][0] = __builtin_amdgcn_mfma_f32_16x16x32_bf16(a2, bg, acc[2][0], 0, 0, 0);
            acc[3][0] = __builtin_amdgcn_mfma_f32_16x16x32_bf16(a3, bg, acc[3][0], 0, 0, 0);
            acc[0][1] = __builtin_amdgcn_mfma_f32_16x16x32_bf16(a0, bd, acc[0][1], 0, 0, 0);
            acc[1][1] = __builtin_amdgcn_mfma_f32_16x16x32_bf16(a1, bd, acc[1][1], 0, 0, 0);
            acc[2][1] = __builtin_amdgcn_mfma_f32_16x16x32_bf16(a2, bd, acc[2][1], 0, 0, 0);
            acc[3][1] = __builtin_amdgcn_mfma_f32_16x16x32_bf16(a3, bd, acc[3][1], 0, 0, 0);
            if (tau_cur) {
                const bf16x8 bt = *(const bf16x8*)(bp + 256);
                acc[0][2] = __builtin_amdgcn_mfma_f32_16x16x32_bf16(a0, bt, acc[0][2], 0, 0, 0);
                acc[1][2] = __builtin_amdgcn_mfma_f32_16x16x32_bf16(a1, bt, acc[1][2], 0, 0, 0);
                acc[2][2] = __builtin_amdgcn_mfma_f32_16x16x32_bf16(a2, bt, acc[2][2], 0, 0, 0);
                acc[3][2] = __builtin_amdgcn_mfma_f32_16x16x32_bf16(a3, bt, acc[3][2], 0, 0, 0);
            }
        }
        if (w < 6) WRITEW(cb ^ 1, w + 1);    // cvt + LDS-write next window
        __syncthreads();                     // window boundary (the only barrier)
    }

    // ---- epilogue: this wave's 64 rows x 16 j (R2-verbatim math) ----
    const int j = jglob + t;
    const float bgj = b_gd[j];
    const float bdj = b_gd[HID + j];
    const float btj = b_tau[j];
    const float dcj = dconst[j];
    #pragma unroll
    for (int rf = 0; rf < 4; ++rf) {
        #pragma unroll
        for (int r = 0; r < 4; ++r) {
            const int row = rt * 64 + rf * 16 + q * 4 + r;
            const float gv = acc[rf][0][r] + bgj;
            const float dv = acc[rf][1][r] + bdj;
            const float tp = acc[rf][2][r] + btj;
            const float hv = h_ltc[(size_t)row * HID + j];
            const float sig = __builtin_amdgcn_rcpf(1.0f + __expf(-gv));
            const float th  = 1.0f - 2.0f * __builtin_amdgcn_rcpf(__expf(2.0f * dv) + 1.0f);
            const float tau = fmaxf(tp, 0.0f) + __logf(1.0f + __expf(-fabsf(tp)));
            out[(size_t)row * HID + j] = (sig * th - hv) * __builtin_amdgcn_rcpf(tau + dcj);
        }
    }
}

// ---------------------------------------------------------------------------
extern "C" void kernel_launch(void* const* d_in, const int* in_sizes, int n_in,
                              void* d_out, int out_size, void* d_ws, size_t ws_size,
                              hipStream_t stream) {
    // setup_inputs order: t, h_ltc, x_t, context, W_gd, b_gd, W_tau, b_tau, gleak, cm
    const float* h_ltc = (const float*)d_in[1];
    const float* x_t   = (const float*)d_in[2];
    const float* ctx   = (const float*)d_in[3];
    const float* W_gd  = (const float*)d_in[4];
    const float* b_gd  = (const float*)d_in[5];
    const float* W_tau = (const float*)d_in[6];
    const float* b_tau = (const float*)d_in[7];
    const float* gleak = (const float*)d_in[8];
    const float* cm    = (const float*)d_in[9];

    char* ws = (char*)d_ws;
    __hip_bfloat16* B_stage = (__hip_bfloat16*)ws;      // 8*112*192*8*2 = 2,752,512 B
    float* dconst = (float*)(ws + 2752512);             // 2,048 B

    pack_B<<<672, 256, 0, stream>>>(W_gd, W_tau, gleak, cm, B_stage, dconst);
    ltc_gemm<<<1024, 512, 0, stream>>>(x_t, h_ltc, ctx, B_stage, b_gd, b_tau, dconst,
                                       (float*)d_out);
}